// Round 9
// baseline (175.383 us; speedup 1.0000x reference)
//
#include <hip/hip_runtime.h>

#define TWO_PI 6.28318530717958647692f

// ---- f16x2-packed LDS staging ----
typedef __fp16 h2v __attribute__((ext_vector_type(2)));
union PK { h2v h; unsigned int u; };

__device__ __forceinline__ unsigned pkf16(float2 z) {
    PK p; p.h = __builtin_amdgcn_cvt_pkrtz(z.x, z.y); return p.u;
}
__device__ __forceinline__ float2 upkf16(unsigned u) {
    PK p; p.u = u; return make_float2((float)p.h[0], (float)p.h[1]);
}

// ---- elementwise float2 helpers ----
__device__ __forceinline__ float2 vadd(float2 a, float2 b) { return make_float2(a.x + b.x, a.y + b.y); }
__device__ __forceinline__ float2 vsub(float2 a, float2 b) { return make_float2(a.x - b.x, a.y - b.y); }
__device__ __forceinline__ float2 iperp(float2 z) { return make_float2(-z.y, z.x); }   // i*z

__device__ __forceinline__ float2 cmul(float2 a, float2 b) {
    float2 p = iperp(a);
    return make_float2(fmaf(b.y, p.x, b.x * a.x), fmaf(b.y, p.y, b.x * a.y));
}

template<int SIGN>
__device__ __forceinline__ float2 twm(float2 z, float wr, float wi) {
    float2 p = iperp(z);
    const float swi = (SIGN > 0) ? wi : -wi;
    return make_float2(fmaf(swi, p.x, wr * z.x), fmaf(swi, p.y, wr * z.y));
}

// e^{S*i*th} for th in [0, 0.37]: Taylor, err < 2e-7 on this range.
__device__ __forceinline__ float2 eiw(float th, float S) {
    float t2 = th * th;
    float sn = th * (1.0f + t2 * (-1.0f / 6.0f + t2 * (1.0f / 120.0f)));
    float cs = 1.0f + t2 * (-0.5f + t2 * (1.0f / 24.0f + t2 * (-1.0f / 720.0f)));
    return make_float2(cs, S * sn);
}

// v[1..15] *= w^idx via w^{4a+b} = (w^4)^a * w^b (depth ~6)
__device__ __forceinline__ void twiddle_pows(float2* v, float2 w) {
    float2 w2 = cmul(w, w);
    float2 w3 = cmul(w2, w);
    float2 w4 = cmul(w2, w2);
    float2 A1 = w4;
    float2 A2 = cmul(w4, w4);
    float2 A3 = cmul(A2, w4);
    #pragma unroll
    for (int a = 0; a < 4; ++a) {
        v[a * 4 + 1] = cmul(v[a * 4 + 1], w);
        v[a * 4 + 2] = cmul(v[a * 4 + 2], w2);
        v[a * 4 + 3] = cmul(v[a * 4 + 3], w3);
    }
    #pragma unroll
    for (int b = 0; b < 4; ++b) {
        v[4 + b]  = cmul(v[4 + b],  A1);
        v[8 + b]  = cmul(v[8 + b],  A2);
        v[12 + b] = cmul(v[12 + b], A3);
    }
}

// v[4a+b] *= base * w^{4a+b}
__device__ __forceinline__ void twiddle_pows_base(float2* v, float2 w, float2 base) {
    float2 w2 = cmul(w, w);
    float2 w3 = cmul(w2, w);
    float2 w4 = cmul(w2, w2);
    float2 A0 = base;
    float2 A1 = cmul(base, w4);
    float2 A2 = cmul(A1, w4);
    float2 A3 = cmul(A2, w4);
    #pragma unroll
    for (int a = 0; a < 4; ++a) {
        v[a * 4 + 1] = cmul(v[a * 4 + 1], w);
        v[a * 4 + 2] = cmul(v[a * 4 + 2], w2);
        v[a * 4 + 3] = cmul(v[a * 4 + 3], w3);
    }
    #pragma unroll
    for (int b = 0; b < 4; ++b) {
        v[b]      = cmul(v[b],      A0);
        v[4 + b]  = cmul(v[4 + b],  A1);
        v[8 + b]  = cmul(v[8 + b],  A2);
        v[12 + b] = cmul(v[12 + b], A3);
    }
}

template<int SIGN>
__device__ __forceinline__ void bf4core(float2 a, float2 b, float2 c, float2 d,
                                        float2& ac, float2& as, float2& bd, float2& ib) {
    ac = vadd(a, c); as = vsub(a, c);
    bd = vadd(b, d);
    float2 bs = vsub(b, d);
    ib = (SIGN > 0) ? make_float2(-bs.y, bs.x) : make_float2(bs.y, -bs.x);
}

// 16-point DFT, in-place. OUTSEL: 0 = all; 1 = only v[4..11]; 2 = only v[0..7].
template<int SIGN, int OUTSEL>
__device__ __forceinline__ void fft16(float2* v) {
    float2 t[16];
    #pragma unroll
    for (int k1 = 0; k1 < 4; ++k1) {
        float2 ac, as, bd, ib;
        bf4core<SIGN>(v[k1], v[k1 + 4], v[k1 + 8], v[k1 + 12], ac, as, bd, ib);
        t[k1 * 4 + 0] = vadd(ac, bd);
        t[k1 * 4 + 1] = vadd(as, ib);
        t[k1 * 4 + 2] = vsub(ac, bd);
        t[k1 * 4 + 3] = vsub(as, ib);
    }
    const float c1 = 0.92387953251128674f;     // cos(pi/8)
    const float s1 = 0.38268343236508977f;     // sin(pi/8)
    const float c2 = 0.70710678118654752f;     // cos(pi/4)
    t[5]  = twm<SIGN>(t[5],  c1,  s1);
    t[6]  = twm<SIGN>(t[6],  c2,  c2);
    t[7]  = twm<SIGN>(t[7],  s1,  c1);
    t[9]  = twm<SIGN>(t[9],  c2,  c2);
    t[10] = twm<SIGN>(t[10], 0.f, 1.f);
    t[11] = twm<SIGN>(t[11], -c2, c2);
    t[13] = twm<SIGN>(t[13], s1,  c1);
    t[14] = twm<SIGN>(t[14], -c2, c2);
    t[15] = twm<SIGN>(t[15], -c1, -s1);
    #pragma unroll
    for (int n2 = 0; n2 < 4; ++n2) {
        float2 ac, as, bd, ib;
        bf4core<SIGN>(t[n2], t[4 + n2], t[8 + n2], t[12 + n2], ac, as, bd, ib);
        if (OUTSEL != 1) v[n2 + 0]  = vadd(ac, bd);
        v[n2 + 4]  = vadd(as, ib);
        if (OUTSEL != 2) v[n2 + 8]  = vsub(ac, bd);
        if (OUTSEL == 0) v[n2 + 12] = vsub(as, ib);
    }
}

// 4096-pt DFT, 256 threads, radix-16 x3, f16x2-packed LDS (16384 B), 2 barriers.
// k = k1 + 16*k2 + 256*k3 ; n = n3 + 16*n2 + 256*n1.
// Swizzle SWZ2(i) = i ^ ((i>>4)&15) ^ (((i>>8)&1)<<4): 2-way (free) banks in
// all phases; hand-factored into dual-base + immediate-offset address forms.
// Step-2 writes back into the slots it read -> no barrier between its r/w.
template<int SIGN, int OUTSEL>
__device__ __forceinline__ void fft4096(float2* v, unsigned* s, int t) {
    const float S = (float)SIGN;
    const int lo = t & 15, hi = t >> 4;
    // ---- step 1: thread (k1=lo, k2=hi); DFT over k3 -> n3 ; twiddle W256^{S*n3*k2}
    {
        fft16<SIGN, 0>(v);
        float2 w = eiw(TWO_PI * (float)hi * (1.0f / 256.0f), S);
        twiddle_pows(v, w);
        // SWZ2(hi*256 + lo*16 + n3) = D + (n3^lo), D = hi*256 + (lo*16 ^ ((hi&1)<<4))
        unsigned* wp = s + hi * 256 + ((lo * 16) ^ ((hi & 1) << 4));
        #pragma unroll
        for (int n3 = 0; n3 < 16; ++n3)
            wp[n3 ^ lo] = pkf16(v[n3]);
    }
    __syncthreads();
    // ---- step 2: thread (n3=lo, k1=hi); DFT over k2 -> n2 ; twiddle W4096^{S*(n3+16*n2)*k1}
    {
        // SWZ2(k2*256 + hi*16 + lo): even k2=2j -> pe[j*512]; odd k2=2j+1 -> po[j*512]
        const int C = hi * 16 + (lo ^ hi);
        unsigned* pe = s + C;
        unsigned* po = s + 256 + (C ^ 16);
        #pragma unroll
        for (int j = 0; j < 8; ++j) {
            v[2 * j]     = upkf16(pe[j * 512]);
            v[2 * j + 1] = upkf16(po[j * 512]);
        }
        fft16<SIGN, 0>(v);
        float2 base = eiw(TWO_PI * (float)(lo * hi) * (1.0f / 4096.0f), S);
        float2 wst  = eiw(TWO_PI * (float)hi * (1.0f / 256.0f), S);
        twiddle_pows_base(v, wst, base);
        // write back into the SAME slots read (per-thread private) -> no barrier
        #pragma unroll
        for (int j = 0; j < 8; ++j) {
            pe[j * 512] = pkf16(v[2 * j]);
            po[j * 512] = pkf16(v[2 * j + 1]);
        }
    }
    __syncthreads();
    // ---- step 3: thread (n3=lo, n2=hi); DFT over k1 -> n1
    {
        // SWZ2(hi*256 + k1*16 + lo) = hi*256 + (k1^(hi&1))*16 + (lo^k1)
        //   even k1: fe + k1*16 + (lo^k1); odd k1: fo + k1*16 + (lo^k1)
        const int p16 = (hi & 1) << 4;
        unsigned* fe = s + hi * 256 + p16;
        unsigned* fo = s + hi * 256 - p16;
        #pragma unroll
        for (int k1 = 0; k1 < 16; ++k1) {
            unsigned* f = (k1 & 1) ? fo : fe;
            v[k1] = upkf16(f[k1 * 16 + (lo ^ k1)]);
        }
        fft16<SIGN, OUTSEL>(v);
    }
}

// Stage 1: forward FFT of reflect-padded x. xh[b*2048 + k], k in [0,2048).
// f32 LDS staging not needed here for accuracy because kfwd is only 32 blocks
// and feeds kinv2; keep f16 staging for symmetry (error budget checked).
__global__ __launch_bounds__(256) void kfwd(const float* __restrict__ x,
                                            float2* __restrict__ xh) {
    __shared__ unsigned sbuf[4096];
    const int t = threadIdx.x, b = blockIdx.x;
    const float* xr = x + b * 2048;
    float2 v[16];
    #pragma unroll
    for (int k3 = 0; k3 < 16; ++k3) {
        int j = t + 256 * k3 - 1024;           // reflect pad
        j = (j < 0) ? -j : ((j >= 2048) ? (4094 - j) : j);
        v[k3] = make_float2(xr[j], 0.0f);
    }
    fft4096<-1, 2>(v, sbuf, t);
    float2* xo = xh + b * 2048;
    #pragma unroll
    for (int n1 = 0; n1 < 8; ++n1)
        xo[t + 256 * n1] = v[n1];
}

// Stage 2 (packed pairs): Hermitian-symmetrize scales a0=2p, a1=2p+1; pack
// Z = Za + i*Zb; one complex iFFT -> row a0 in .x, a1 in .y. Crop n1 in [4,12).
__global__ __launch_bounds__(256, 8) void kinv2(const float* __restrict__ Psih,
                                                const float2* __restrict__ xh,
                                                float* __restrict__ out) {
    __shared__ unsigned sbuf[4096];
    const int t = threadIdx.x;
    const int blk = blockIdx.x;                // 4096 = 32 b * 128 pairs
    const int ap = blk & 127, b = blk >> 7;
    const int a0 = ap * 2;
    const float* pa = Psih + (size_t)a0 * 4096;
    const float* pb = pa + 4096;
    const float2* xr = xh + (size_t)b * 2048;
    const float s = 0.5f / 4096.0f;            // Hermitian 1/2 * ifft 1/N
    float2 v[16];
    #pragma unroll
    for (int k3 = 0; k3 < 8; ++k3) {           // k in [0,2048): Z = s*X*(Pa+iPb)
        int k = t + 256 * k3;
        float px = pa[k] * s, py = pb[k] * s;
        float2 X = xr[k];
        v[k3] = make_float2(px * X.x - py * X.y, py * X.x + px * X.y);
    }
    #pragma unroll
    for (int k3 = 8; k3 < 16; ++k3) {          // k in [2048,4096): Z = s*conj(X[m])*(Pa[m]+iPb[m])
        int m = 4096 - (t + 256 * k3);         // m in [1,2048]
        float px = pa[m] * s, py = pb[m] * s;  // P[2048]==0
        float2 X = xr[m & 2047];               // only m==2048 remapped (P==0 there)
        v[k3] = make_float2(px * X.x + py * X.y, py * X.x - px * X.y);
    }
    fft4096<1, 1>(v, sbuf, t);
    float* o0 = out + ((long long)b * 256 + a0) * 2048 + t;
    #pragma unroll
    for (int n1 = 4; n1 < 12; ++n1) {          // n = t + 256*n1, crop [1024,3072)
        o0[256 * (n1 - 4)]        = v[n1].x;   // row a0
        o0[2048 + 256 * (n1 - 4)] = v[n1].y;   // row a1
    }
}

// Fallback if workspace unusable: fused fwd+mul+inv, packed pairs.
__global__ __launch_bounds__(256, 8) void kfused2(const float* __restrict__ x,
                                                  const float* __restrict__ Psih,
                                                  float* __restrict__ out) {
    __shared__ unsigned sbuf[4096];
    const int t = threadIdx.x;
    const int blk = blockIdx.x;
    const int ap = blk & 127, b = blk >> 7;
    const int a0 = ap * 2;
    const float* xr = x + b * 2048;
    float2 v[16];
    #pragma unroll
    for (int k3 = 0; k3 < 16; ++k3) {
        int j = t + 256 * k3 - 1024;
        j = (j < 0) ? -j : ((j >= 2048) ? (4094 - j) : j);
        v[k3] = make_float2(xr[j], 0.0f);
    }
    fft4096<-1, 0>(v, sbuf, t);
    const float* pa = Psih + (size_t)a0 * 4096;
    const float* pb = pa + 4096;
    const float s = 0.5f / 4096.0f;
    #pragma unroll
    for (int n1 = 0; n1 < 16; ++n1) {
        int k = t + 256 * n1;
        int idx = (k < 2048) ? k : (4096 - k);
        float px = pa[idx] * s, py = pb[idx] * s;
        float2 X = v[n1];
        v[n1] = make_float2(px * X.x - py * X.y, py * X.x + px * X.y);
    }
    __syncthreads();
    fft4096<1, 1>(v, sbuf, t);
    float* o0 = out + ((long long)b * 256 + a0) * 2048 + t;
    #pragma unroll
    for (int n1 = 4; n1 < 12; ++n1) {
        o0[256 * (n1 - 4)]        = v[n1].x;
        o0[2048 + 256 * (n1 - 4)] = v[n1].y;
    }
}

extern "C" void kernel_launch(void* const* d_in, const int* in_sizes, int n_in,
                              void* d_out, int out_size, void* d_ws, size_t ws_size,
                              hipStream_t stream) {
    const float* x = (const float*)d_in[0];
    const float* Psih = (const float*)d_in[1];
    float* out = (float*)d_out;
    const size_t xh_bytes = (size_t)32 * 2048 * sizeof(float2);   // 512 KB
    if (ws_size >= xh_bytes && d_ws != nullptr) {
        float2* xh = (float2*)d_ws;
        kfwd<<<32, 256, 0, stream>>>(x, xh);
        kinv2<<<4096, 256, 0, stream>>>(Psih, xh, out);
    } else {
        kfused2<<<4096, 256, 0, stream>>>(x, Psih, out);
    }
}

// Round 10
// 120.842 us; speedup vs baseline: 1.4513x; 1.4513x over previous
//
#include <hip/hip_runtime.h>

#define TWO_PI 6.28318530717958647692f

// ---- f16x2-packed LDS staging ----
typedef __fp16 h2v __attribute__((ext_vector_type(2)));
union PK { h2v h; unsigned int u; };

__device__ __forceinline__ unsigned pkf16(float2 z) {
    PK p; p.h = __builtin_amdgcn_cvt_pkrtz(z.x, z.y); return p.u;
}
__device__ __forceinline__ float2 upkf16(unsigned u) {
    PK p; p.u = u; return make_float2((float)p.h[0], (float)p.h[1]);
}

// ---- elementwise float2 helpers ----
__device__ __forceinline__ float2 vadd(float2 a, float2 b) { return make_float2(a.x + b.x, a.y + b.y); }
__device__ __forceinline__ float2 vsub(float2 a, float2 b) { return make_float2(a.x - b.x, a.y - b.y); }
__device__ __forceinline__ float2 iperp(float2 z) { return make_float2(-z.y, z.x); }   // i*z

__device__ __forceinline__ float2 cmul(float2 a, float2 b) {
    float2 p = iperp(a);
    return make_float2(fmaf(b.y, p.x, b.x * a.x), fmaf(b.y, p.y, b.x * a.y));
}

template<int SIGN>
__device__ __forceinline__ float2 twm(float2 z, float wr, float wi) {
    float2 p = iperp(z);
    const float swi = (SIGN > 0) ? wi : -wi;
    return make_float2(fmaf(swi, p.x, wr * z.x), fmaf(swi, p.y, wr * z.y));
}

// e^{S*i*th} for th in [0, 0.37]: Taylor, err < 2e-7 on this range.
__device__ __forceinline__ float2 eiw(float th, float S) {
    float t2 = th * th;
    float sn = th * (1.0f + t2 * (-1.0f / 6.0f + t2 * (1.0f / 120.0f)));
    float cs = 1.0f + t2 * (-0.5f + t2 * (1.0f / 24.0f + t2 * (-1.0f / 720.0f)));
    return make_float2(cs, S * sn);
}

// v[1..15] *= w^idx via w^{4a+b} = (w^4)^a * w^b (depth ~6)
__device__ __forceinline__ void twiddle_pows(float2* v, float2 w) {
    float2 w2 = cmul(w, w);
    float2 w3 = cmul(w2, w);
    float2 w4 = cmul(w2, w2);
    float2 A1 = w4;
    float2 A2 = cmul(w4, w4);
    float2 A3 = cmul(A2, w4);
    #pragma unroll
    for (int a = 0; a < 4; ++a) {
        v[a * 4 + 1] = cmul(v[a * 4 + 1], w);
        v[a * 4 + 2] = cmul(v[a * 4 + 2], w2);
        v[a * 4 + 3] = cmul(v[a * 4 + 3], w3);
    }
    #pragma unroll
    for (int b = 0; b < 4; ++b) {
        v[4 + b]  = cmul(v[4 + b],  A1);
        v[8 + b]  = cmul(v[8 + b],  A2);
        v[12 + b] = cmul(v[12 + b], A3);
    }
}

// v[4a+b] *= base * w^{4a+b}
__device__ __forceinline__ void twiddle_pows_base(float2* v, float2 w, float2 base) {
    float2 w2 = cmul(w, w);
    float2 w3 = cmul(w2, w);
    float2 w4 = cmul(w2, w2);
    float2 A0 = base;
    float2 A1 = cmul(base, w4);
    float2 A2 = cmul(A1, w4);
    float2 A3 = cmul(A2, w4);
    #pragma unroll
    for (int a = 0; a < 4; ++a) {
        v[a * 4 + 1] = cmul(v[a * 4 + 1], w);
        v[a * 4 + 2] = cmul(v[a * 4 + 2], w2);
        v[a * 4 + 3] = cmul(v[a * 4 + 3], w3);
    }
    #pragma unroll
    for (int b = 0; b < 4; ++b) {
        v[b]      = cmul(v[b],      A0);
        v[4 + b]  = cmul(v[4 + b],  A1);
        v[8 + b]  = cmul(v[8 + b],  A2);
        v[12 + b] = cmul(v[12 + b], A3);
    }
}

template<int SIGN>
__device__ __forceinline__ void bf4core(float2 a, float2 b, float2 c, float2 d,
                                        float2& ac, float2& as, float2& bd, float2& ib) {
    ac = vadd(a, c); as = vsub(a, c);
    bd = vadd(b, d);
    float2 bs = vsub(b, d);
    ib = (SIGN > 0) ? make_float2(-bs.y, bs.x) : make_float2(bs.y, -bs.x);
}

// 16-point DFT, in-place. OUTSEL: 0 = all; 1 = only v[4..11]; 2 = only v[0..7].
template<int SIGN, int OUTSEL>
__device__ __forceinline__ void fft16(float2* v) {
    float2 t[16];
    #pragma unroll
    for (int k1 = 0; k1 < 4; ++k1) {
        float2 ac, as, bd, ib;
        bf4core<SIGN>(v[k1], v[k1 + 4], v[k1 + 8], v[k1 + 12], ac, as, bd, ib);
        t[k1 * 4 + 0] = vadd(ac, bd);
        t[k1 * 4 + 1] = vadd(as, ib);
        t[k1 * 4 + 2] = vsub(ac, bd);
        t[k1 * 4 + 3] = vsub(as, ib);
    }
    const float c1 = 0.92387953251128674f;     // cos(pi/8)
    const float s1 = 0.38268343236508977f;     // sin(pi/8)
    const float c2 = 0.70710678118654752f;     // cos(pi/4)
    t[5]  = twm<SIGN>(t[5],  c1,  s1);
    t[6]  = twm<SIGN>(t[6],  c2,  c2);
    t[7]  = twm<SIGN>(t[7],  s1,  c1);
    t[9]  = twm<SIGN>(t[9],  c2,  c2);
    t[10] = twm<SIGN>(t[10], 0.f, 1.f);
    t[11] = twm<SIGN>(t[11], -c2, c2);
    t[13] = twm<SIGN>(t[13], s1,  c1);
    t[14] = twm<SIGN>(t[14], -c2, c2);
    t[15] = twm<SIGN>(t[15], -c1, -s1);
    #pragma unroll
    for (int n2 = 0; n2 < 4; ++n2) {
        float2 ac, as, bd, ib;
        bf4core<SIGN>(t[n2], t[4 + n2], t[8 + n2], t[12 + n2], ac, as, bd, ib);
        if (OUTSEL != 1) v[n2 + 0]  = vadd(ac, bd);
        v[n2 + 4]  = vadd(as, ib);
        if (OUTSEL != 2) v[n2 + 8]  = vsub(ac, bd);
        if (OUTSEL == 0) v[n2 + 12] = vsub(as, ib);
    }
}

// 4096-pt DFT, 256 threads, radix-16 x3, f16x2-packed LDS (16384 B), 2 barriers.
// k = k1 + 16*k2 + 256*k3 ; n = n3 + 16*n2 + 256*n1.
// Swizzle SWZ2(i) = i ^ ((i>>4)&15) ^ (((i>>8)&1)<<4): 2-way (free) banks in
// all phases; hand-factored into dual-base + immediate-offset address forms.
// Step-2 writes back into the slots it read -> no barrier between its r/w.
template<int SIGN, int OUTSEL>
__device__ __forceinline__ void fft4096(float2* v, unsigned* s, int t) {
    const float S = (float)SIGN;
    const int lo = t & 15, hi = t >> 4;
    // ---- step 1: thread (k1=lo, k2=hi); DFT over k3 -> n3 ; twiddle W256^{S*n3*k2}
    {
        fft16<SIGN, 0>(v);
        float2 w = eiw(TWO_PI * (float)hi * (1.0f / 256.0f), S);
        twiddle_pows(v, w);
        // SWZ2(hi*256 + lo*16 + n3) = D + (n3^lo), D = hi*256 + (lo*16 ^ ((hi&1)<<4))
        unsigned* wp = s + hi * 256 + ((lo * 16) ^ ((hi & 1) << 4));
        #pragma unroll
        for (int n3 = 0; n3 < 16; ++n3)
            wp[n3 ^ lo] = pkf16(v[n3]);
    }
    __syncthreads();
    // ---- step 2: thread (n3=lo, k1=hi); DFT over k2 -> n2 ; twiddle W4096^{S*(n3+16*n2)*k1}
    {
        // SWZ2(k2*256 + hi*16 + lo): even k2=2j -> pe[j*512]; odd k2=2j+1 -> po[j*512]
        const int C = hi * 16 + (lo ^ hi);
        unsigned* pe = s + C;
        unsigned* po = s + 256 + (C ^ 16);
        #pragma unroll
        for (int j = 0; j < 8; ++j) {
            v[2 * j]     = upkf16(pe[j * 512]);
            v[2 * j + 1] = upkf16(po[j * 512]);
        }
        fft16<SIGN, 0>(v);
        float2 base = eiw(TWO_PI * (float)(lo * hi) * (1.0f / 4096.0f), S);
        float2 wst  = eiw(TWO_PI * (float)hi * (1.0f / 256.0f), S);
        twiddle_pows_base(v, wst, base);
        // write back into the SAME slots read (per-thread private) -> no barrier
        #pragma unroll
        for (int j = 0; j < 8; ++j) {
            pe[j * 512] = pkf16(v[2 * j]);
            po[j * 512] = pkf16(v[2 * j + 1]);
        }
    }
    __syncthreads();
    // ---- step 3: thread (n3=lo, n2=hi); DFT over k1 -> n1
    {
        // SWZ2(hi*256 + k1*16 + lo) = hi*256 + (k1^(hi&1))*16 + (lo^k1)
        const int p16 = (hi & 1) << 4;
        unsigned* fe = s + hi * 256 + p16;
        unsigned* fo = s + hi * 256 - p16;
        #pragma unroll
        for (int k1 = 0; k1 < 16; ++k1) {
            unsigned* f = (k1 & 1) ? fo : fe;
            v[k1] = upkf16(f[k1 * 16 + (lo ^ k1)]);
        }
        fft16<SIGN, OUTSEL>(v);
    }
}

// Stage 1: forward FFT of reflect-padded x. xh[b*2048 + k], k in [0,2048).
__global__ __launch_bounds__(256) void kfwd(const float* __restrict__ x,
                                            float2* __restrict__ xh) {
    __shared__ unsigned sbuf[4096];
    const int t = threadIdx.x, b = blockIdx.x;
    const float* xr = x + b * 2048;
    float2 v[16];
    #pragma unroll
    for (int k3 = 0; k3 < 16; ++k3) {
        int j = t + 256 * k3 - 1024;           // reflect pad
        j = (j < 0) ? -j : ((j >= 2048) ? (4094 - j) : j);
        v[k3] = make_float2(xr[j], 0.0f);
    }
    fft4096<-1, 2>(v, sbuf, t);
    float2* xo = xh + b * 2048;
    #pragma unroll
    for (int n1 = 0; n1 < 8; ++n1)
        xo[t + 256 * n1] = v[n1];
}

// Stage 2 (packed pairs): Hermitian-symmetrize scales a0=2p, a1=2p+1; pack
// Z = Za + i*Zb; one complex iFFT -> row a0 in .x, a1 in .y. Crop n1 in [4,12).
// launch_bounds(256,6): VGPR cap ~85 (round-7 structure fit in 64 -> no spill);
// 16 KB LDS allows up to 8 blocks/CU if allocator lands <=64 VGPR.
__global__ __launch_bounds__(256, 6) void kinv2(const float* __restrict__ Psih,
                                                const float2* __restrict__ xh,
                                                float* __restrict__ out) {
    __shared__ unsigned sbuf[4096];
    const int t = threadIdx.x;
    const int blk = blockIdx.x;                // 4096 = 32 b * 128 pairs
    const int ap = blk & 127, b = blk >> 7;
    const int a0 = ap * 2;
    const float* pa = Psih + (size_t)a0 * 4096;
    const float* pb = pa + 4096;
    const float2* xr = xh + (size_t)b * 2048;
    const float s = 0.5f / 4096.0f;            // Hermitian 1/2 * ifft 1/N
    float2 v[16];
    #pragma unroll
    for (int k3 = 0; k3 < 8; ++k3) {           // k in [0,2048): Z = s*X*(Pa+iPb)
        int k = t + 256 * k3;
        float px = pa[k] * s, py = pb[k] * s;
        float2 X = xr[k];
        v[k3] = make_float2(px * X.x - py * X.y, py * X.x + px * X.y);
    }
    #pragma unroll
    for (int k3 = 8; k3 < 16; ++k3) {          // k in [2048,4096): Z = s*conj(X[m])*(Pa[m]+iPb[m])
        int m = 4096 - (t + 256 * k3);         // m in [1,2048]
        float px = pa[m] * s, py = pb[m] * s;  // P[2048]==0
        float2 X = xr[m & 2047];               // only m==2048 remapped (P==0 there)
        v[k3] = make_float2(px * X.x + py * X.y, py * X.x - px * X.y);
    }
    fft4096<1, 1>(v, sbuf, t);
    float* o0 = out + ((long long)b * 256 + a0) * 2048 + t;
    #pragma unroll
    for (int n1 = 4; n1 < 12; ++n1) {          // n = t + 256*n1, crop [1024,3072)
        o0[256 * (n1 - 4)]        = v[n1].x;   // row a0
        o0[2048 + 256 * (n1 - 4)] = v[n1].y;   // row a1
    }
}

// Fallback if workspace unusable: fused fwd+mul+inv, packed pairs.
__global__ __launch_bounds__(256, 6) void kfused2(const float* __restrict__ x,
                                                  const float* __restrict__ Psih,
                                                  float* __restrict__ out) {
    __shared__ unsigned sbuf[4096];
    const int t = threadIdx.x;
    const int blk = blockIdx.x;
    const int ap = blk & 127, b = blk >> 7;
    const int a0 = ap * 2;
    const float* xr = x + b * 2048;
    float2 v[16];
    #pragma unroll
    for (int k3 = 0; k3 < 16; ++k3) {
        int j = t + 256 * k3 - 1024;
        j = (j < 0) ? -j : ((j >= 2048) ? (4094 - j) : j);
        v[k3] = make_float2(xr[j], 0.0f);
    }
    fft4096<-1, 0>(v, sbuf, t);
    const float* pa = Psih + (size_t)a0 * 4096;
    const float* pb = pa + 4096;
    const float s = 0.5f / 4096.0f;
    #pragma unroll
    for (int n1 = 0; n1 < 16; ++n1) {
        int k = t + 256 * n1;
        int idx = (k < 2048) ? k : (4096 - k);
        float px = pa[idx] * s, py = pb[idx] * s;
        float2 X = v[n1];
        v[n1] = make_float2(px * X.x - py * X.y, py * X.x + px * X.y);
    }
    __syncthreads();
    fft4096<1, 1>(v, sbuf, t);
    float* o0 = out + ((long long)b * 256 + a0) * 2048 + t;
    #pragma unroll
    for (int n1 = 4; n1 < 12; ++n1) {
        o0[256 * (n1 - 4)]        = v[n1].x;
        o0[2048 + 256 * (n1 - 4)] = v[n1].y;
    }
}

extern "C" void kernel_launch(void* const* d_in, const int* in_sizes, int n_in,
                              void* d_out, int out_size, void* d_ws, size_t ws_size,
                              hipStream_t stream) {
    const float* x = (const float*)d_in[0];
    const float* Psih = (const float*)d_in[1];
    float* out = (float*)d_out;
    const size_t xh_bytes = (size_t)32 * 2048 * sizeof(float2);   // 512 KB
    if (ws_size >= xh_bytes && d_ws != nullptr) {
        float2* xh = (float2*)d_ws;
        kfwd<<<32, 256, 0, stream>>>(x, xh);
        kinv2<<<4096, 256, 0, stream>>>(Psih, xh, out);
    } else {
        kfused2<<<4096, 256, 0, stream>>>(x, Psih, out);
    }
}

// Round 11
// 101.772 us; speedup vs baseline: 1.7233x; 1.1874x over previous
//
#include <hip/hip_runtime.h>

#define TWO_PI 6.28318530717958647692f

// ---- f16x2-packed LDS staging ----
typedef __fp16 h2v __attribute__((ext_vector_type(2)));
union PK { h2v h; unsigned int u; };

__device__ __forceinline__ unsigned pkf16(float2 z) {
    PK p; p.h = __builtin_amdgcn_cvt_pkrtz(z.x, z.y); return p.u;
}
__device__ __forceinline__ float2 upkf16(unsigned u) {
    PK p; p.u = u; return make_float2((float)p.h[0], (float)p.h[1]);
}

// ---- elementwise float2 helpers ----
__device__ __forceinline__ float2 vadd(float2 a, float2 b) { return make_float2(a.x + b.x, a.y + b.y); }
__device__ __forceinline__ float2 vsub(float2 a, float2 b) { return make_float2(a.x - b.x, a.y - b.y); }
__device__ __forceinline__ float2 iperp(float2 z) { return make_float2(-z.y, z.x); }   // i*z

__device__ __forceinline__ float2 cmul(float2 a, float2 b) {
    float2 p = iperp(a);
    return make_float2(fmaf(b.y, p.x, b.x * a.x), fmaf(b.y, p.y, b.x * a.y));
}

template<int SIGN>
__device__ __forceinline__ float2 twm(float2 z, float wr, float wi) {
    float2 p = iperp(z);
    const float swi = (SIGN > 0) ? wi : -wi;
    return make_float2(fmaf(swi, p.x, wr * z.x), fmaf(swi, p.y, wr * z.y));
}

// e^{S*i*th} for th in [0, 0.37]: Taylor, err < 2e-7 on this range.
__device__ __forceinline__ float2 eiw(float th, float S) {
    float t2 = th * th;
    float sn = th * (1.0f + t2 * (-1.0f / 6.0f + t2 * (1.0f / 120.0f)));
    float cs = 1.0f + t2 * (-0.5f + t2 * (1.0f / 24.0f + t2 * (-1.0f / 720.0f)));
    return make_float2(cs, S * sn);
}

// v[1..15] *= w^idx via w^{4a+b} = (w^4)^a * w^b (depth ~6)
__device__ __forceinline__ void twiddle_pows(float2* v, float2 w) {
    float2 w2 = cmul(w, w);
    float2 w3 = cmul(w2, w);
    float2 w4 = cmul(w2, w2);
    float2 A1 = w4;
    float2 A2 = cmul(w4, w4);
    float2 A3 = cmul(A2, w4);
    #pragma unroll
    for (int a = 0; a < 4; ++a) {
        v[a * 4 + 1] = cmul(v[a * 4 + 1], w);
        v[a * 4 + 2] = cmul(v[a * 4 + 2], w2);
        v[a * 4 + 3] = cmul(v[a * 4 + 3], w3);
    }
    #pragma unroll
    for (int b = 0; b < 4; ++b) {
        v[4 + b]  = cmul(v[4 + b],  A1);
        v[8 + b]  = cmul(v[8 + b],  A2);
        v[12 + b] = cmul(v[12 + b], A3);
    }
}

// v[4a+b] *= base * w^{4a+b}
__device__ __forceinline__ void twiddle_pows_base(float2* v, float2 w, float2 base) {
    float2 w2 = cmul(w, w);
    float2 w3 = cmul(w2, w);
    float2 w4 = cmul(w2, w2);
    float2 A0 = base;
    float2 A1 = cmul(base, w4);
    float2 A2 = cmul(A1, w4);
    float2 A3 = cmul(A2, w4);
    #pragma unroll
    for (int a = 0; a < 4; ++a) {
        v[a * 4 + 1] = cmul(v[a * 4 + 1], w);
        v[a * 4 + 2] = cmul(v[a * 4 + 2], w2);
        v[a * 4 + 3] = cmul(v[a * 4 + 3], w3);
    }
    #pragma unroll
    for (int b = 0; b < 4; ++b) {
        v[b]      = cmul(v[b],      A0);
        v[4 + b]  = cmul(v[4 + b],  A1);
        v[8 + b]  = cmul(v[8 + b],  A2);
        v[12 + b] = cmul(v[12 + b], A3);
    }
}

template<int SIGN>
__device__ __forceinline__ void bf4core(float2 a, float2 b, float2 c, float2 d,
                                        float2& ac, float2& as, float2& bd, float2& ib) {
    ac = vadd(a, c); as = vsub(a, c);
    bd = vadd(b, d);
    float2 bs = vsub(b, d);
    ib = (SIGN > 0) ? make_float2(-bs.y, bs.x) : make_float2(bs.y, -bs.x);
}

// 16-point DFT, in-place. OUTSEL: 0 = all; 1 = only v[4..11]; 2 = only v[0..7].
template<int SIGN, int OUTSEL>
__device__ __forceinline__ void fft16(float2* v) {
    float2 t[16];
    #pragma unroll
    for (int k1 = 0; k1 < 4; ++k1) {
        float2 ac, as, bd, ib;
        bf4core<SIGN>(v[k1], v[k1 + 4], v[k1 + 8], v[k1 + 12], ac, as, bd, ib);
        t[k1 * 4 + 0] = vadd(ac, bd);
        t[k1 * 4 + 1] = vadd(as, ib);
        t[k1 * 4 + 2] = vsub(ac, bd);
        t[k1 * 4 + 3] = vsub(as, ib);
    }
    const float c1 = 0.92387953251128674f;     // cos(pi/8)
    const float s1 = 0.38268343236508977f;     // sin(pi/8)
    const float c2 = 0.70710678118654752f;     // cos(pi/4)
    t[5]  = twm<SIGN>(t[5],  c1,  s1);
    t[6]  = twm<SIGN>(t[6],  c2,  c2);
    t[7]  = twm<SIGN>(t[7],  s1,  c1);
    t[9]  = twm<SIGN>(t[9],  c2,  c2);
    t[10] = twm<SIGN>(t[10], 0.f, 1.f);
    t[11] = twm<SIGN>(t[11], -c2, c2);
    t[13] = twm<SIGN>(t[13], s1,  c1);
    t[14] = twm<SIGN>(t[14], -c2, c2);
    t[15] = twm<SIGN>(t[15], -c1, -s1);
    #pragma unroll
    for (int n2 = 0; n2 < 4; ++n2) {
        float2 ac, as, bd, ib;
        bf4core<SIGN>(t[n2], t[4 + n2], t[8 + n2], t[12 + n2], ac, as, bd, ib);
        if (OUTSEL != 1) v[n2 + 0]  = vadd(ac, bd);
        v[n2 + 4]  = vadd(as, ib);
        if (OUTSEL != 2) v[n2 + 8]  = vsub(ac, bd);
        if (OUTSEL == 0) v[n2 + 12] = vsub(as, ib);
    }
}

// 4096-pt DFT, 256 threads, radix-16 x3, f16x2-packed LDS (16384 B), 2 barriers.
// k = k1 + 16*k2 + 256*k3 ; n = n3 + 16*n2 + 256*n1.
// Swizzle SWZ2(i) = i ^ ((i>>4)&15) ^ (((i>>8)&1)<<4): 2-way (free) banks in
// all phases; hand-factored into dual-base + immediate-offset address forms.
// Step-2 writes back into the slots it read -> no barrier between its r/w.
template<int SIGN, int OUTSEL>
__device__ __forceinline__ void fft4096(float2* v, unsigned* s, int t) {
    const float S = (float)SIGN;
    const int lo = t & 15, hi = t >> 4;
    // ---- step 1: thread (k1=lo, k2=hi); DFT over k3 -> n3 ; twiddle W256^{S*n3*k2}
    {
        fft16<SIGN, 0>(v);
        float2 w = eiw(TWO_PI * (float)hi * (1.0f / 256.0f), S);
        twiddle_pows(v, w);
        // SWZ2(hi*256 + lo*16 + n3) = D + (n3^lo), D = hi*256 + (lo*16 ^ ((hi&1)<<4))
        unsigned* wp = s + hi * 256 + ((lo * 16) ^ ((hi & 1) << 4));
        #pragma unroll
        for (int n3 = 0; n3 < 16; ++n3)
            wp[n3 ^ lo] = pkf16(v[n3]);
    }
    __syncthreads();
    // ---- step 2: thread (n3=lo, k1=hi); DFT over k2 -> n2 ; twiddle W4096^{S*(n3+16*n2)*k1}
    {
        // SWZ2(k2*256 + hi*16 + lo): even k2=2j -> pe[j*512]; odd k2=2j+1 -> po[j*512]
        const int C = hi * 16 + (lo ^ hi);
        unsigned* pe = s + C;
        unsigned* po = s + 256 + (C ^ 16);
        #pragma unroll
        for (int j = 0; j < 8; ++j) {
            v[2 * j]     = upkf16(pe[j * 512]);
            v[2 * j + 1] = upkf16(po[j * 512]);
        }
        fft16<SIGN, 0>(v);
        float2 base = eiw(TWO_PI * (float)(lo * hi) * (1.0f / 4096.0f), S);
        float2 wst  = eiw(TWO_PI * (float)hi * (1.0f / 256.0f), S);
        twiddle_pows_base(v, wst, base);
        // write back into the SAME slots read (per-thread private) -> no barrier
        #pragma unroll
        for (int j = 0; j < 8; ++j) {
            pe[j * 512] = pkf16(v[2 * j]);
            po[j * 512] = pkf16(v[2 * j + 1]);
        }
    }
    __syncthreads();
    // ---- step 3: thread (n3=lo, n2=hi); DFT over k1 -> n1
    {
        // SWZ2(hi*256 + k1*16 + lo) = hi*256 + (k1^(hi&1))*16 + (lo^k1)
        const int p16 = (hi & 1) << 4;
        unsigned* fe = s + hi * 256 + p16;
        unsigned* fo = s + hi * 256 - p16;
        #pragma unroll
        for (int k1 = 0; k1 < 16; ++k1) {
            unsigned* f = (k1 & 1) ? fo : fe;
            v[k1] = upkf16(f[k1 * 16 + (lo ^ k1)]);
        }
        fft16<SIGN, OUTSEL>(v);
    }
}

// Stage 1: forward FFT of reflect-padded x. xh[b*2048 + k], k in [0,2048).
__global__ __launch_bounds__(256) void kfwd(const float* __restrict__ x,
                                            float2* __restrict__ xh) {
    __shared__ unsigned sbuf[4096];
    const int t = threadIdx.x, b = blockIdx.x;
    const float* xr = x + b * 2048;
    float2 v[16];
    #pragma unroll
    for (int k3 = 0; k3 < 16; ++k3) {
        int j = t + 256 * k3 - 1024;           // reflect pad
        j = (j < 0) ? -j : ((j >= 2048) ? (4094 - j) : j);
        v[k3] = make_float2(xr[j], 0.0f);
    }
    fft4096<-1, 2>(v, sbuf, t);
    float2* xo = xh + b * 2048;
    #pragma unroll
    for (int n1 = 0; n1 < 8; ++n1)
        xo[t + 256 * n1] = v[n1];
}

// Stage 2 (packed pairs): Hermitian-symmetrize scales a0=2p, a1=2p+1; pack
// Z = Za + i*Zb; one complex iFFT -> row a0 in .x, a1 in .y. Crop n1 in [4,12).
// NO min-waves bound: rounds 9/10 proved forcing occupancy (8->VGPR32, 6->VGPR40)
// causes scratch spills (WRITE_SIZE 65->326/180 MB). Natural allocation = 64 VGPR,
// zero spill; 16 KB LDS then allows up to 8 blocks/CU on its own.
__global__ __launch_bounds__(256) void kinv2(const float* __restrict__ Psih,
                                             const float2* __restrict__ xh,
                                             float* __restrict__ out) {
    __shared__ unsigned sbuf[4096];
    const int t = threadIdx.x;
    const int blk = blockIdx.x;                // 4096 = 32 b * 128 pairs
    const int ap = blk & 127, b = blk >> 7;
    const int a0 = ap * 2;
    const float* pa = Psih + (size_t)a0 * 4096;
    const float* pb = pa + 4096;
    const float2* xr = xh + (size_t)b * 2048;
    const float s = 0.5f / 4096.0f;            // Hermitian 1/2 * ifft 1/N
    float2 v[16];
    #pragma unroll
    for (int k3 = 0; k3 < 8; ++k3) {           // k in [0,2048): Z = s*X*(Pa+iPb)
        int k = t + 256 * k3;
        float px = pa[k] * s, py = pb[k] * s;
        float2 X = xr[k];
        v[k3] = make_float2(px * X.x - py * X.y, py * X.x + px * X.y);
    }
    #pragma unroll
    for (int k3 = 8; k3 < 16; ++k3) {          // k in [2048,4096): Z = s*conj(X[m])*(Pa[m]+iPb[m])
        int m = 4096 - (t + 256 * k3);         // m in [1,2048]
        float px = pa[m] * s, py = pb[m] * s;  // P[2048]==0
        float2 X = xr[m & 2047];               // only m==2048 remapped (P==0 there)
        v[k3] = make_float2(px * X.x + py * X.y, py * X.x - px * X.y);
    }
    fft4096<1, 1>(v, sbuf, t);
    float* o0 = out + ((long long)b * 256 + a0) * 2048 + t;
    #pragma unroll
    for (int n1 = 4; n1 < 12; ++n1) {          // n = t + 256*n1, crop [1024,3072)
        o0[256 * (n1 - 4)]        = v[n1].x;   // row a0
        o0[2048 + 256 * (n1 - 4)] = v[n1].y;   // row a1
    }
}

// Fallback if workspace unusable: fused fwd+mul+inv, packed pairs.
__global__ __launch_bounds__(256) void kfused2(const float* __restrict__ x,
                                               const float* __restrict__ Psih,
                                               float* __restrict__ out) {
    __shared__ unsigned sbuf[4096];
    const int t = threadIdx.x;
    const int blk = blockIdx.x;
    const int ap = blk & 127, b = blk >> 7;
    const int a0 = ap * 2;
    const float* xr = x + b * 2048;
    float2 v[16];
    #pragma unroll
    for (int k3 = 0; k3 < 16; ++k3) {
        int j = t + 256 * k3 - 1024;
        j = (j < 0) ? -j : ((j >= 2048) ? (4094 - j) : j);
        v[k3] = make_float2(xr[j], 0.0f);
    }
    fft4096<-1, 0>(v, sbuf, t);
    const float* pa = Psih + (size_t)a0 * 4096;
    const float* pb = pa + 4096;
    const float s = 0.5f / 4096.0f;
    #pragma unroll
    for (int n1 = 0; n1 < 16; ++n1) {
        int k = t + 256 * n1;
        int idx = (k < 2048) ? k : (4096 - k);
        float px = pa[idx] * s, py = pb[idx] * s;
        float2 X = v[n1];
        v[n1] = make_float2(px * X.x - py * X.y, py * X.x + px * X.y);
    }
    __syncthreads();
    fft4096<1, 1>(v, sbuf, t);
    float* o0 = out + ((long long)b * 256 + a0) * 2048 + t;
    #pragma unroll
    for (int n1 = 4; n1 < 12; ++n1) {
        o0[256 * (n1 - 4)]        = v[n1].x;
        o0[2048 + 256 * (n1 - 4)] = v[n1].y;
    }
}

extern "C" void kernel_launch(void* const* d_in, const int* in_sizes, int n_in,
                              void* d_out, int out_size, void* d_ws, size_t ws_size,
                              hipStream_t stream) {
    const float* x = (const float*)d_in[0];
    const float* Psih = (const float*)d_in[1];
    float* out = (float*)d_out;
    const size_t xh_bytes = (size_t)32 * 2048 * sizeof(float2);   // 512 KB
    if (ws_size >= xh_bytes && d_ws != nullptr) {
        float2* xh = (float2*)d_ws;
        kfwd<<<32, 256, 0, stream>>>(x, xh);
        kinv2<<<4096, 256, 0, stream>>>(Psih, xh, out);
    } else {
        kfused2<<<4096, 256, 0, stream>>>(x, Psih, out);
    }
}